// Round 6
// baseline (72.566 us; speedup 1.0000x reference)
//
#include <hip/hip_runtime.h>
#include <stdint.h>

typedef __fp16 fp16x2 __attribute__((ext_vector_type(2)));
typedef _Float16 half4 __attribute__((ext_vector_type(4)));
typedef _Float16 half8 __attribute__((ext_vector_type(8)));
typedef float f32x4 __attribute__((ext_vector_type(4)));

#define NS 4096
#define NTOT 8192
#define DD 256
#define NBLK 2080   // 528 SS lower-tri + 528 TT lower-tri + 1024 ST full
#define BK 32       // K-step; 8 K-tiles of 32 over K=256

// workspace layout (bytes)
#define OFF_X16   0                        // 8192*256*2 = 4 MB fp16
#define OFF_SQ    (4*1024*1024)            // 8192 floats
#define OFF_COLP  (OFF_SQ + 32*1024)       // 256*256 floats = 256 KB
#define OFF_BP    (OFF_COLP + 256*1024)    // 2080 floats
#define OFF_SCAL  (OFF_BP + 2080*4)        // 1 float (exp2 scale)

// ---------------------------------------------------------------- K1: prep
__global__ __launch_bounds__(256) void mmd_prep(const float* __restrict__ S,
                                                const float* __restrict__ T,
                                                _Float16* __restrict__ X16,
                                                float* __restrict__ sq,
                                                float* __restrict__ colpart) {
    __shared__ float cl[4][256];
    const int b = blockIdx.x, tid = threadIdx.x;
    const int lane = tid & 63, w = tid >> 6;
    f32x4 cacc = {0.f, 0.f, 0.f, 0.f};
    #pragma unroll
    for (int it = 0; it < 8; ++it) {
        const int row = b * 32 + it * 4 + w;     // wave-uniform row
        const float* src = (row < NS) ? (S + (size_t)row * DD)
                                      : (T + (size_t)(row - NS) * DD);
        const f32x4 v = *(const f32x4*)(src + lane * 4);
        cacc += v;
        float vv = v.x * v.x + v.y * v.y + v.z * v.z + v.w * v.w;
        half4 h = { (_Float16)v.x, (_Float16)v.y, (_Float16)v.z, (_Float16)v.w };
        *(half4*)(X16 + (size_t)row * DD + lane * 4) = h;
        #pragma unroll
        for (int off = 32; off; off >>= 1) vv += __shfl_down(vv, off);
        if (lane == 0) sq[row] = vv;
    }
    *(f32x4*)&cl[w][lane * 4] = cacc;
    __syncthreads();
    colpart[b * 256 + tid] = cl[0][tid] + cl[1][tid] + cl[2][tid] + cl[3][tid];
}

// ---------------------------------------------------------------- K2: bandwidth
__global__ __launch_bounds__(512) void mmd_bw(const float* __restrict__ colpart,
                                              const float* __restrict__ sq,
                                              float* __restrict__ scal) {
    __shared__ float csh[256];
    __shared__ double sd[8], sf[8];
    const int t = threadIdx.x;
    const int hf = t >> 8, c = t & 255;
    float cs = 0.0f;
    #pragma unroll 4
    for (int b = 0; b < 128; ++b) cs += colpart[(hf * 128 + b) * 256 + c];
    if (hf) csh[c] = cs;
    __syncthreads();
    double s2 = 0.0;
    if (!hf) { const double tot = (double)cs + (double)csh[c]; s2 = tot * tot; }
    float qs = 0.0f;
    #pragma unroll
    for (int k = 0; k < 16; ++k) qs += sq[t + 512 * k];
    double qd = (double)qs;
    const int lane = t & 63, w = t >> 6;
    #pragma unroll
    for (int off = 32; off; off >>= 1) {
        s2 += __shfl_down(s2, off);
        qd += __shfl_down(qd, off);
    }
    if (lane == 0) { sd[w] = s2; sf[w] = qd; }
    __syncthreads();
    if (t == 0) {
        double s2t = 0.0, qt = 0.0;
        #pragma unroll
        for (int i = 0; i < 8; ++i) { s2t += sd[i]; qt += sf[i]; }
        const double n = (double)NTOT;
        const double sumd2 = 2.0 * n * qt - 2.0 * s2t;
        double bwv = sumd2 / (n * n - n);
        bwv = bwv / 4.0;   // KERNEL_MUL^(KERNEL_NUM//2) = 2^2
        // e4 = exp(-d2/(16*bw)) = exp2(-d2 * cl2)
        scal[0] = (float)(1.0 / (16.0 * bwv * 0.6931471805599453));
    }
}

// ---------------------------------------------------------------- K3: main GEMM+kernel
// 128x128 tile, BK=32 double-buffered, 2-phase prefetch (STAGE(t+1) before
// COMPUTE(t), one barrier per K-step). FRAGMENT-ORDERED LDS: tile stored as
// 8 regions x [kc 0..3][rowlow 0..15] 16B chunks, so each wave fragment
// ds_read_b128 is a contiguous 1024B block (conflict-free by construction);
// global_load_lds dest = wave-uniform base + lane*16 (HW constraint), the
// PER-LANE GLOBAL SOURCE carries the permutation. pk-fp16 epilogue.
__global__ __launch_bounds__(256) void mmd_main(const _Float16* __restrict__ X16,
                                                const float* __restrict__ sq,
                                                const float* __restrict__ scal,
                                                float* __restrict__ blockpart) {
    __shared__ _Float16 As[2][128 * BK];
    __shared__ _Float16 Bs[2][128 * BK];

    // T1: XCD swizzle (2080 % 8 == 0 -> bijective simple form)
    const int bid = (blockIdx.x % 8) * (NBLK / 8) + blockIdx.x / 8;
    int br, bc;
    float wfac;
    if (bid < 1056) {
        int t = bid, base = 0;
        if (t >= 528) { t -= 528; base = 32; }
        int i = (int)((sqrtf(8.0f * (float)t + 1.0f) - 1.0f) * 0.5f);
        while ((i + 1) * (i + 2) / 2 <= t) ++i;
        while (i * (i + 1) / 2 > t) --i;
        const int j = t - i * (i + 1) / 2;
        br = base + i; bc = base + j;
        wfac = (i == j) ? 1.0f : 2.0f;   // off-diag tile counts for (i,j) and (j,i)
    } else {
        const int t = bid - 1056;
        br = t >> 5; bc = 32 + (t & 31);
        wfac = -2.0f;                    // loss has -2*xy
    }
    const int row0 = br * 128, col0 = bc * 128;
    const int tid = threadIdx.x;
    const int lane = tid & 63;
    const int w = tid >> 6;
    const int wrd = (w >> 1) * 4, wcd = (w & 1) * 4;   // region bases (row/16)
    const int wr = wrd * 16, wc = wcd * 16;

    f32x4 acc[4][4] = {};

    // staging map: dest chunk c = q*256 + tid ; rh=c>>6, kc=(c>>4)&3, rl=c&15
    const int rh0 = tid >> 6;
    const int kc  = (tid >> 4) & 3;
    const int rl  = tid & 15;
    const int rr0 = rh0 * 16 + rl;                 // q=0 row within tile
    const size_t goA0 = (size_t)(row0 + rr0) * DD + kc * 8;
    const size_t goB0 = (size_t)(col0 + rr0) * DD + kc * 8;
    const size_t goA1 = goA0 + (size_t)64 * DD;    // q=1: rows +64
    const size_t goB1 = goB0 + (size_t)64 * DD;

    auto STAGE = [&](int s, int kt) {
        const int k0 = kt * BK;
        __builtin_amdgcn_global_load_lds(
            (const __attribute__((address_space(1))) uint32_t*)(X16 + goA0 + k0),
            (__attribute__((address_space(3))) uint32_t*)&As[s][tid * 8], 16, 0, 0);
        __builtin_amdgcn_global_load_lds(
            (const __attribute__((address_space(1))) uint32_t*)(X16 + goB0 + k0),
            (__attribute__((address_space(3))) uint32_t*)&Bs[s][tid * 8], 16, 0, 0);
        __builtin_amdgcn_global_load_lds(
            (const __attribute__((address_space(1))) uint32_t*)(X16 + goA1 + k0),
            (__attribute__((address_space(3))) uint32_t*)&As[s][2048 + tid * 8], 16, 0, 0);
        __builtin_amdgcn_global_load_lds(
            (const __attribute__((address_space(1))) uint32_t*)(X16 + goB1 + k0),
            (__attribute__((address_space(3))) uint32_t*)&Bs[s][2048 + tid * 8], 16, 0, 0);
    };

    auto COMPUTE = [&](int s) {
        half8 a[4], b[4];
        #pragma unroll
        for (int m = 0; m < 4; ++m)
            a[m] = *(const half8*)&As[s][(wrd + m) * 512 + lane * 8];
        #pragma unroll
        for (int n = 0; n < 4; ++n)
            b[n] = *(const half8*)&Bs[s][(wcd + n) * 512 + lane * 8];
        __builtin_amdgcn_s_setprio(1);
        #pragma unroll
        for (int m = 0; m < 4; ++m)
            #pragma unroll
            for (int n = 0; n < 4; ++n)
                acc[m][n] = __builtin_amdgcn_mfma_f32_16x16x32_f16(
                    a[m], b[n], acc[m][n], 0, 0, 0);
        __builtin_amdgcn_s_setprio(0);
    };

    STAGE(0, 0);
    __syncthreads();                 // drains prologue stage
    #pragma unroll
    for (int kt = 0; kt < 7; ++kt) {
        STAGE((kt + 1) & 1, kt + 1); // prefetch next tile (other slot)
        COMPUTE(kt & 1);             // ds_read + MFMA current tile
        __syncthreads();             // loads had whole MFMA phase to land
    }
    COMPUTE(1);

    // epilogue: e4 = exp2(-d2*cl2); kernel sum = e+e^2+e^4+e^8+e^16 via pk-fp16.
    // x = g*2cl2 + (sip+sjp), sip=-cl2*si, sjp=-cl2*sj; clamp x<=0 (== d2>=0).
    const float cl2 = scal[0];
    const float c2  = 2.0f * cl2;
    const int c_lo = lane & 15, r_hi = lane >> 4;
    float sjp[4], sip[4][4];
    #pragma unroll
    for (int n = 0; n < 4; ++n) sjp[n] = -cl2 * sq[col0 + wc + n * 16 + c_lo];
    #pragma unroll
    for (int m = 0; m < 4; ++m)
        #pragma unroll
        for (int r = 0; r < 4; ++r)
            sip[m][r] = -cl2 * sq[row0 + wr + m * 16 + r_hi * 4 + r];

    float part = 0.0f;
    const fp16x2 one2 = {(__fp16)1.0f, (__fp16)1.0f};
    #pragma unroll
    for (int m = 0; m < 4; ++m)
        #pragma unroll
        for (int n = 0; n < 4; ++n)
            #pragma unroll
            for (int rp = 0; rp < 2; ++rp) {
                const float x0 = fminf(fmaf(acc[m][n][2 * rp],     c2,
                                            sip[m][2 * rp]     + sjp[n]), 0.0f);
                const float x1 = fminf(fmaf(acc[m][n][2 * rp + 1], c2,
                                            sip[m][2 * rp + 1] + sjp[n]), 0.0f);
                const float e0 = exp2f(x0);
                const float e1 = exp2f(x1);
                fp16x2 h  = __builtin_amdgcn_cvt_pkrtz(e0, e1);
                fp16x2 p2 = h * h;           // e^2
                fp16x2 ks = h + p2;
                p2 = p2 * p2; ks += p2;      // e^4
                p2 = p2 * p2; ks += p2;      // e^8
                p2 = p2 * p2; ks += p2;      // e^16
#if __has_builtin(__builtin_amdgcn_fdot2)
                part = __builtin_amdgcn_fdot2(ks, one2, part, false);
#else
                part += (float)ks.x + (float)ks.y;
#endif
            }

    #pragma unroll
    for (int off = 32; off > 0; off >>= 1) part += __shfl_down(part, off);
    __shared__ float wsum[4];
    if (lane == 0) wsum[w] = part;
    __syncthreads();
    if (tid == 0)
        blockpart[bid] = (wsum[0] + wsum[1] + wsum[2] + wsum[3]) * wfac;
}

// ---------------------------------------------------------------- K4: final reduce
__global__ __launch_bounds__(256) void mmd_final(const float* __restrict__ blockpart,
                                                 float* __restrict__ out) {
    const int t = threadIdx.x;
    double acc = 0.0;
    for (int i = t; i < NBLK; i += 256) acc += (double)blockpart[i];
    #pragma unroll
    for (int off = 32; off > 0; off >>= 1) acc += __shfl_down(acc, off);
    __shared__ double sd[4];
    const int lane = t & 63, w = t >> 6;
    if (lane == 0) sd[w] = acc;
    __syncthreads();
    if (t == 0) {
        const double tot = (sd[0] + sd[1] + sd[2] + sd[3]) /
                           ((double)NS * (double)NS);
        out[0] = (float)fmax(tot, 0.0);
    }
}

// ---------------------------------------------------------------- launch
extern "C" void kernel_launch(void* const* d_in, const int* in_sizes, int n_in,
                              void* d_out, int out_size, void* d_ws, size_t ws_size,
                              hipStream_t stream) {
    const float* S = (const float*)d_in[0];
    const float* T = (const float*)d_in[1];
    char* ws = (char*)d_ws;
    _Float16* X16   = (_Float16*)(ws + OFF_X16);
    float* sq       = (float*)(ws + OFF_SQ);
    float* colpart  = (float*)(ws + OFF_COLP);
    float* blockpart= (float*)(ws + OFF_BP);
    float* scal     = (float*)(ws + OFF_SCAL);

    mmd_prep<<<256, 256, 0, stream>>>(S, T, X16, sq, colpart);
    mmd_bw<<<1, 512, 0, stream>>>(colpart, sq, scal);
    mmd_main<<<NBLK, 256, 0, stream>>>(X16, sq, scal, blockpart);
    mmd_final<<<1, 256, 0, stream>>>(blockpart, (float*)d_out);
}

// Round 7
// 63.850 us; speedup vs baseline: 1.1365x; 1.1365x over previous
//
#include <hip/hip_runtime.h>
#include <stdint.h>

typedef _Float16 half4 __attribute__((ext_vector_type(4)));
typedef _Float16 half8 __attribute__((ext_vector_type(8)));
typedef float f32x4 __attribute__((ext_vector_type(4)));

#define NS 4096
#define NTOT 8192
#define DD 256
#define NBLK 2080   // 528 SS lower-tri + 528 TT lower-tri + 1024 ST full
#define BK 32       // K-step; 8 K-tiles of 32 over K=256

// X16 "tiled4" layout: addr(r,k) = (r>>4)*4096 + (k>>3)*128 + (r&15)*8 + (k&7)
// -> each (16-row, 32-col) K-subtile is one contiguous 1KB block; main-kernel
// staging reads are wave-uniform base + lane*16B (perfectly coalesced), and
// the linear LDS dest is fragment-ordered (conflict-free ds_read_b128).

// workspace layout (bytes)
#define OFF_X16   0                        // 8192*256*2 = 4 MB fp16 (tiled4)
#define OFF_SQ    (4*1024*1024)            // 8192 floats
#define OFF_COLP  (OFF_SQ + 32*1024)       // 256*256 floats = 256 KB
#define OFF_BP    (OFF_COLP + 256*1024)    // 2080 floats
#define OFF_SCAL  (OFF_BP + 2080*4)        // 1 float (exp2 scale)

// ---------------------------------------------------------------- K1: prep
// 256 blocks x 256 threads; block b handles rows [32b, 32b+32) in two
// 16-row halves. LDS reorder -> 8KB contiguous tiled4 writes.
__global__ __launch_bounds__(256) void mmd_prep(const float* __restrict__ S,
                                                const float* __restrict__ T,
                                                _Float16* __restrict__ X16,
                                                float* __restrict__ sq,
                                                float* __restrict__ colpart) {
    __shared__ _Float16 tile[16][264];     // +8 halves pad: conflict-free reorder
    __shared__ float cl[4][256];
    const int b = blockIdx.x, tid = threadIdx.x;
    const int lane = tid & 63, w = tid >> 6;
    f32x4 cacc = {0.f, 0.f, 0.f, 0.f};
    #pragma unroll
    for (int h = 0; h < 2; ++h) {
        #pragma unroll
        for (int rr = 0; rr < 4; ++rr) {
            const int row = b * 32 + h * 16 + w * 4 + rr;   // wave-uniform
            const float* src = (row < NS) ? (S + (size_t)row * DD)
                                          : (T + (size_t)(row - NS) * DD);
            const f32x4 v = *(const f32x4*)(src + lane * 4);
            cacc += v;
            float vv = v.x * v.x + v.y * v.y + v.z * v.z + v.w * v.w;
            half4 hx = { (_Float16)v.x, (_Float16)v.y, (_Float16)v.z, (_Float16)v.w };
            *(half4*)&tile[w * 4 + rr][lane * 4] = hx;
            #pragma unroll
            for (int off = 32; off; off >>= 1) vv += __shfl_down(vv, off);
            if (lane == 0) sq[row] = vv;
        }
        __syncthreads();
        _Float16* dst = X16 + (size_t)(b * 2 + h) * 4096;
        #pragma unroll
        for (int q = 0; q < 2; ++q) {
            const int c = q * 256 + tid;                    // chunk = kc*16+rl
            *(half8*)(dst + c * 8) = *(const half8*)&tile[c & 15][(c >> 4) * 8];
        }
        __syncthreads();
    }
    *(f32x4*)&cl[w][lane * 4] = cacc;
    __syncthreads();
    colpart[b * 256 + tid] = cl[0][tid] + cl[1][tid] + cl[2][tid] + cl[3][tid];
}

// ---------------------------------------------------------------- K2: bandwidth
__global__ __launch_bounds__(512) void mmd_bw(const float* __restrict__ colpart,
                                              const float* __restrict__ sq,
                                              float* __restrict__ scal) {
    __shared__ float csh[256];
    __shared__ double sd[8], sf[8];
    const int t = threadIdx.x;
    const int hf = t >> 8, c = t & 255;
    float cs = 0.0f;
    #pragma unroll 4
    for (int b = 0; b < 128; ++b) cs += colpart[(hf * 128 + b) * 256 + c];
    if (hf) csh[c] = cs;
    __syncthreads();
    double s2 = 0.0;
    if (!hf) { const double tot = (double)cs + (double)csh[c]; s2 = tot * tot; }
    float qs = 0.0f;
    #pragma unroll
    for (int k = 0; k < 16; ++k) qs += sq[t + 512 * k];
    double qd = (double)qs;
    const int lane = t & 63, w = t >> 6;
    #pragma unroll
    for (int off = 32; off; off >>= 1) {
        s2 += __shfl_down(s2, off);
        qd += __shfl_down(qd, off);
    }
    if (lane == 0) { sd[w] = s2; sf[w] = qd; }
    __syncthreads();
    if (t == 0) {
        double s2t = 0.0, qt = 0.0;
        #pragma unroll
        for (int i = 0; i < 8; ++i) { s2t += sd[i]; qt += sf[i]; }
        const double n = (double)NTOT;
        const double sumd2 = 2.0 * n * qt - 2.0 * s2t;
        double bwv = sumd2 / (n * n - n);
        bwv = bwv / 4.0;   // KERNEL_MUL^(KERNEL_NUM//2) = 2^2
        // e4 = exp(-d2/(16*bw)) = exp2(-d2 * cl2)
        scal[0] = (float)(1.0 / (16.0 * bwv * 0.6931471805599453));
    }
}

// ---------------------------------------------------------------- K3: main GEMM+kernel
// 128x128 tile, BK=32, 3-slot LDS ring, prefetch distance 2, counted
// s_waitcnt vmcnt(4) + raw s_barrier (never drain-to-0 mid-loop). Staging
// loads are contiguous 1KB per wave (tiled4 X16); LDS fragment-ordered
// (conflict-free, verified 0 conflicts in r6). f32 exp epilogue.
__global__ __launch_bounds__(256) void mmd_main(const _Float16* __restrict__ X16,
                                                const float* __restrict__ sq,
                                                const float* __restrict__ scal,
                                                float* __restrict__ blockpart) {
    __shared__ _Float16 As[3][128 * BK];
    __shared__ _Float16 Bs[3][128 * BK];

    // T1: XCD swizzle (2080 % 8 == 0 -> bijective simple form)
    const int bid = (blockIdx.x % 8) * (NBLK / 8) + blockIdx.x / 8;
    int br, bc;
    float wfac;
    if (bid < 1056) {
        int t = bid, base = 0;
        if (t >= 528) { t -= 528; base = 32; }
        int i = (int)((sqrtf(8.0f * (float)t + 1.0f) - 1.0f) * 0.5f);
        while ((i + 1) * (i + 2) / 2 <= t) ++i;
        while (i * (i + 1) / 2 > t) --i;
        const int j = t - i * (i + 1) / 2;
        br = base + i; bc = base + j;
        wfac = (i == j) ? 1.0f : 2.0f;   // off-diag tile counts for (i,j) and (j,i)
    } else {
        const int t = bid - 1056;
        br = t >> 5; bc = 32 + (t & 31);
        wfac = -2.0f;                    // loss has -2*xy
    }
    const int row0 = br * 128, col0 = bc * 128;
    const int tid = threadIdx.x;
    const int lane = tid & 63;
    const int w = tid >> 6;
    const int wrd = (w >> 1) * 4, wcd = (w & 1) * 4;   // 16-row region bases
    const int wr = wrd * 16, wc = wcd * 16;

    f32x4 acc[4][4] = {};

    // staging: src = wave-uniform base + lane*16B (contiguous 1KB per wave)
    const _Float16* baseA = X16 + (size_t)(row0 >> 4) * 4096
                                + (size_t)(tid >> 6) * 4096 + (size_t)(tid & 63) * 8;
    const _Float16* baseB = X16 + (size_t)(col0 >> 4) * 4096
                                + (size_t)(tid >> 6) * 4096 + (size_t)(tid & 63) * 8;

    auto STAGE = [&](int s, int kt) {
        const int ko = kt * 512;
        __builtin_amdgcn_global_load_lds(
            (const __attribute__((address_space(1))) uint32_t*)(baseA + ko),
            (__attribute__((address_space(3))) uint32_t*)&As[s][tid * 8], 16, 0, 0);
        __builtin_amdgcn_global_load_lds(
            (const __attribute__((address_space(1))) uint32_t*)(baseB + ko),
            (__attribute__((address_space(3))) uint32_t*)&Bs[s][tid * 8], 16, 0, 0);
        __builtin_amdgcn_global_load_lds(
            (const __attribute__((address_space(1))) uint32_t*)(baseA + ko + 16384),
            (__attribute__((address_space(3))) uint32_t*)&As[s][2048 + tid * 8], 16, 0, 0);
        __builtin_amdgcn_global_load_lds(
            (const __attribute__((address_space(1))) uint32_t*)(baseB + ko + 16384),
            (__attribute__((address_space(3))) uint32_t*)&Bs[s][2048 + tid * 8], 16, 0, 0);
    };

    auto COMPUTE = [&](int s) {
        half8 a[4], b[4];
        #pragma unroll
        for (int m = 0; m < 4; ++m)
            a[m] = *(const half8*)&As[s][(wrd + m) * 512 + lane * 8];
        #pragma unroll
        for (int n = 0; n < 4; ++n)
            b[n] = *(const half8*)&Bs[s][(wcd + n) * 512 + lane * 8];
        __builtin_amdgcn_s_setprio(1);
        #pragma unroll
        for (int m = 0; m < 4; ++m)
            #pragma unroll
            for (int n = 0; n < 4; ++n)
                acc[m][n] = __builtin_amdgcn_mfma_f32_16x16x32_f16(
                    a[m], b[n], acc[m][n], 0, 0, 0);
        __builtin_amdgcn_s_setprio(0);
    };

    // prologue: fill the 3-slot ring; wait for tile 0 only (8 of 12 may fly)
    STAGE(0, 0); STAGE(1, 1); STAGE(2, 2);
    asm volatile("s_waitcnt vmcnt(8)" ::: "memory");
    __builtin_amdgcn_s_barrier();

    #pragma unroll
    for (int kt = 0; kt < 8; ++kt) {
        if (kt <= 5) STAGE((kt + 2) % 3, kt + 2);   // prefetch distance 2
        COMPUTE(kt % 3);
        if (kt < 6) {
            // tile kt+1 landed iff outstanding <= 4 (only tile kt+2's loads)
            asm volatile("s_waitcnt vmcnt(4)" ::: "memory");
            __builtin_amdgcn_s_barrier();
        } else if (kt == 6) {
            asm volatile("s_waitcnt vmcnt(0)" ::: "memory");
            __builtin_amdgcn_s_barrier();
        }
    }

    // epilogue: e4 = exp2(-d2*cl2); kernel sum = e+e^2+e^4+e^8+e^16.
    // x = g*2cl2 + (sip+sjp), sip=-cl2*si, sjp=-cl2*sj; clamp x<=0 (== d2>=0).
    const float cl2 = scal[0];
    const float c2  = 2.0f * cl2;
    const int c_lo = lane & 15, r_hi = lane >> 4;
    float sjp[4], sip[4][4];
    #pragma unroll
    for (int n = 0; n < 4; ++n) sjp[n] = -cl2 * sq[col0 + wc + n * 16 + c_lo];
    #pragma unroll
    for (int m = 0; m < 4; ++m)
        #pragma unroll
        for (int r = 0; r < 4; ++r)
            sip[m][r] = -cl2 * sq[row0 + wr + m * 16 + r_hi * 4 + r];

    float part = 0.0f;
    #pragma unroll
    for (int m = 0; m < 4; ++m)
        #pragma unroll
        for (int n = 0; n < 4; ++n)
            #pragma unroll
            for (int r = 0; r < 4; ++r) {
                const float x = fminf(fmaf(acc[m][n][r], c2,
                                           sip[m][r] + sjp[n]), 0.0f);
                float e = exp2f(x);
                float ksum = e;
                e *= e; ksum += e;   // ^2
                e *= e; ksum += e;   // ^4
                e *= e; ksum += e;   // ^8
                e *= e; ksum += e;   // ^16
                part += ksum;
            }

    #pragma unroll
    for (int off = 32; off > 0; off >>= 1) part += __shfl_down(part, off);
    __shared__ float wsum[4];
    if (lane == 0) wsum[w] = part;
    __syncthreads();
    if (tid == 0)
        blockpart[bid] = (wsum[0] + wsum[1] + wsum[2] + wsum[3]) * wfac;
}

// ---------------------------------------------------------------- K4: final reduce
__global__ __launch_bounds__(256) void mmd_final(const float* __restrict__ blockpart,
                                                 float* __restrict__ out) {
    const int t = threadIdx.x;
    double acc = 0.0;
    for (int i = t; i < NBLK; i += 256) acc += (double)blockpart[i];
    #pragma unroll
    for (int off = 32; off > 0; off >>= 1) acc += __shfl_down(acc, off);
    __shared__ double sd[4];
    const int lane = t & 63, w = t >> 6;
    if (lane == 0) sd[w] = acc;
    __syncthreads();
    if (t == 0) {
        const double tot = (sd[0] + sd[1] + sd[2] + sd[3]) /
                           ((double)NS * (double)NS);
        out[0] = (float)fmax(tot, 0.0);
    }
}

// ---------------------------------------------------------------- launch
extern "C" void kernel_launch(void* const* d_in, const int* in_sizes, int n_in,
                              void* d_out, int out_size, void* d_ws, size_t ws_size,
                              hipStream_t stream) {
    const float* S = (const float*)d_in[0];
    const float* T = (const float*)d_in[1];
    char* ws = (char*)d_ws;
    _Float16* X16   = (_Float16*)(ws + OFF_X16);
    float* sq       = (float*)(ws + OFF_SQ);
    float* colpart  = (float*)(ws + OFF_COLP);
    float* blockpart= (float*)(ws + OFF_BP);
    float* scal     = (float*)(ws + OFF_SCAL);

    mmd_prep<<<256, 256, 0, stream>>>(S, T, X16, sq, colpart);
    mmd_bw<<<1, 512, 0, stream>>>(colpart, sq, scal);
    mmd_main<<<NBLK, 256, 0, stream>>>(X16, sq, scal, blockpart);
    mmd_final<<<1, 256, 0, stream>>>(blockpart, (float*)d_out);
}

// Round 8
// 57.028 us; speedup vs baseline: 1.2725x; 1.1196x over previous
//
#include <hip/hip_runtime.h>
#include <stdint.h>

typedef _Float16 half4 __attribute__((ext_vector_type(4)));
typedef _Float16 half8 __attribute__((ext_vector_type(8)));
typedef float f32x4 __attribute__((ext_vector_type(4)));

#define NS 4096
#define NTOT 8192
#define DD 256
#define NBLK 2080   // 528 SS lower-tri + 528 TT lower-tri + 1024 ST full

// X16 "tiled4" layout: addr(r,k) = (r>>4)*4096 + (k>>3)*128 + (r&15)*8 + (k&7)
// -> each (16-row, 32-col) K-subtile is one contiguous 1KB block, each 16-row
// full-K panel is one contiguous 8KB block; a 128-row A-panel is 64KB linear.

// workspace layout (bytes)
#define OFF_X16   0                        // 8192*256*2 = 4 MB fp16 (tiled4)
#define OFF_SQ    (4*1024*1024)            // 8192 floats
#define OFF_COLP  (OFF_SQ + 32*1024)       // 256*256 floats = 256 KB
#define OFF_BP    (OFF_COLP + 256*1024)    // 2080 floats
#define OFF_SCAL  (OFF_BP + 2080*4)        // 1 float (exp2 scale)

// ---------------------------------------------------------------- K1: prep
// 256 blocks x 256 threads; block b handles rows [32b, 32b+32) in two
// 16-row halves. LDS reorder -> 8KB contiguous tiled4 writes.
__global__ __launch_bounds__(256) void mmd_prep(const float* __restrict__ S,
                                                const float* __restrict__ T,
                                                _Float16* __restrict__ X16,
                                                float* __restrict__ sq,
                                                float* __restrict__ colpart) {
    __shared__ _Float16 tile[16][264];     // +8 halves pad: conflict-free reorder
    __shared__ float cl[4][256];
    const int b = blockIdx.x, tid = threadIdx.x;
    const int lane = tid & 63, w = tid >> 6;
    f32x4 cacc = {0.f, 0.f, 0.f, 0.f};
    #pragma unroll
    for (int h = 0; h < 2; ++h) {
        #pragma unroll
        for (int rr = 0; rr < 4; ++rr) {
            const int row = b * 32 + h * 16 + w * 4 + rr;   // wave-uniform
            const float* src = (row < NS) ? (S + (size_t)row * DD)
                                          : (T + (size_t)(row - NS) * DD);
            const f32x4 v = *(const f32x4*)(src + lane * 4);
            cacc += v;
            float vv = v.x * v.x + v.y * v.y + v.z * v.z + v.w * v.w;
            half4 hx = { (_Float16)v.x, (_Float16)v.y, (_Float16)v.z, (_Float16)v.w };
            *(half4*)&tile[w * 4 + rr][lane * 4] = hx;
            #pragma unroll
            for (int off = 32; off; off >>= 1) vv += __shfl_down(vv, off);
            if (lane == 0) sq[row] = vv;
        }
        __syncthreads();
        _Float16* dst = X16 + (size_t)(b * 2 + h) * 4096;
        #pragma unroll
        for (int q = 0; q < 2; ++q) {
            const int c = q * 256 + tid;                    // chunk = kc*16+rl
            *(half8*)(dst + c * 8) = *(const half8*)&tile[c & 15][(c >> 4) * 8];
        }
        __syncthreads();
    }
    *(f32x4*)&cl[w][lane * 4] = cacc;
    __syncthreads();
    colpart[b * 256 + tid] = cl[0][tid] + cl[1][tid] + cl[2][tid] + cl[3][tid];
}

// ---------------------------------------------------------------- K2: bandwidth
// 1 block, 1024 threads (16 waves). Group g (t>>8) sums 64 block-partials of
// column c (t&255) with a fully-unrolled independent load chain (latency-
// parallel), then LDS-combine. sum(d2) = 2*n*sum(sq) - 2*||colsum||^2.
__global__ __launch_bounds__(1024) void mmd_bw(const float* __restrict__ colpart,
                                               const float* __restrict__ sq,
                                               float* __restrict__ scal) {
    __shared__ float cpart[4][256];
    __shared__ double sd[16], sf[16];
    const int t = threadIdx.x;
    const int c = t & 255, g = t >> 8;
    float cs = 0.0f;
    #pragma unroll
    for (int b = 0; b < 64; ++b) cs += colpart[((g * 64 + b) << 8) | c];
    cpart[g][c] = cs;
    // each thread also sums 8 contiguous sq entries (2 x f32x4)
    const f32x4 q0 = *(const f32x4*)(sq + t * 8);
    const f32x4 q1 = *(const f32x4*)(sq + t * 8 + 4);
    double qd = (double)(q0.x + q0.y + q0.z + q0.w) +
                (double)(q1.x + q1.y + q1.z + q1.w);
    __syncthreads();
    double s2 = 0.0;
    if (g == 0) {
        const double tot = (double)cpart[0][c] + cpart[1][c] +
                           cpart[2][c] + cpart[3][c];
        s2 = tot * tot;
    }
    const int lane = t & 63, w = t >> 6;
    #pragma unroll
    for (int off = 32; off; off >>= 1) {
        s2 += __shfl_down(s2, off);
        qd += __shfl_down(qd, off);
    }
    if (lane == 0) { sd[w] = s2; sf[w] = qd; }
    __syncthreads();
    if (t == 0) {
        double s2t = 0.0, qt = 0.0;
        #pragma unroll
        for (int i = 0; i < 16; ++i) { s2t += sd[i]; qt += sf[i]; }
        const double n = (double)NTOT;
        const double sumd2 = 2.0 * n * qt - 2.0 * s2t;
        double bwv = sumd2 / (n * n - n);
        bwv = bwv / 4.0;   // KERNEL_MUL^(KERNEL_NUM//2) = 2^2
        // e4 = exp(-d2/(16*bw)) = exp2(-d2 * cl2)
        scal[0] = (float)(1.0 / (16.0 * bwv * 0.6931471805599453));
    }
}

// ---------------------------------------------------------------- K3: main GEMM+kernel
// B-panel IN REGISTERS (32 half8 = 128 VGPR per thread, full K=256 for the
// wave's 64-col block); A-panel staged to LDS ONCE (64KB contiguous tiled4,
// 16 global_load_lds per thread). ONE vmcnt(0) + ONE barrier per block,
// zero mid-loop syncs; 128 independent MFMAs per wave. Fused exp epilogue.
__global__ __launch_bounds__(256, 2) void mmd_main(const _Float16* __restrict__ X16,
                                                   const float* __restrict__ sq,
                                                   const float* __restrict__ scal,
                                                   float* __restrict__ blockpart) {
    __shared__ _Float16 As[8 * 4096];      // 64KB A panel, tiled4-linear

    // T1: XCD swizzle (2080 % 8 == 0 -> bijective simple form)
    const int bid = (blockIdx.x % 8) * (NBLK / 8) + blockIdx.x / 8;
    int br, bc;
    float wfac;
    if (bid < 1056) {
        int t = bid, base = 0;
        if (t >= 528) { t -= 528; base = 32; }
        int i = (int)((sqrtf(8.0f * (float)t + 1.0f) - 1.0f) * 0.5f);
        while ((i + 1) * (i + 2) / 2 <= t) ++i;
        while (i * (i + 1) / 2 > t) --i;
        const int j = t - i * (i + 1) / 2;
        br = base + i; bc = base + j;
        wfac = (i == j) ? 1.0f : 2.0f;   // off-diag tile counts for (i,j) and (j,i)
    } else {
        const int t = bid - 1056;
        br = t >> 5; bc = 32 + (t & 31);
        wfac = -2.0f;                    // loss has -2*xy
    }
    const int row0 = br * 128, col0 = bc * 128;
    const int tid = threadIdx.x;
    const int lane = tid & 63;
    const int w = tid >> 6;
    const int wrd = (w >> 1) * 4, wcd = (w & 1) * 4;   // 16-row region bases
    const int wr = wrd * 16, wc = wcd * 16;
    const int rA = lane & 15, hi = lane >> 4;

    // ---- B -> registers (program order BEFORE the wait; loads can't sink
    // past the "memory" asm). Fragment (n,kt) of lane: tiled4 address.
    const _Float16* Bbase = X16 + ((size_t)(col0 >> 4) + wcd) * 4096
                                + hi * 128 + rA * 8;
    half8 breg[4][8];
    #pragma unroll
    for (int n = 0; n < 4; ++n)
        #pragma unroll
        for (int kt = 0; kt < 8; ++kt)
            breg[n][kt] = *(const half8*)(Bbase + n * 4096 + kt * 512);

    // ---- A panel -> LDS (contiguous 64KB, lane-linear dest)
    const _Float16* Abase = X16 + (size_t)(row0 >> 4) * 4096;
    #pragma unroll
    for (int i = 0; i < 16; ++i) {
        const int c = i * 256 + tid;
        __builtin_amdgcn_global_load_lds(
            (const __attribute__((address_space(1))) uint32_t*)(Abase + c * 8),
            (__attribute__((address_space(3))) uint32_t*)&As[c * 8], 16, 0, 0);
    }
    asm volatile("s_waitcnt vmcnt(0)" ::: "memory");
    __builtin_amdgcn_s_barrier();

    // ---- K loop: 8 x (4 ds_read_b128 + 16 MFMA), no syncs
    f32x4 acc[4][4] = {};
    #pragma unroll
    for (int kt = 0; kt < 8; ++kt) {
        half8 a[4];
        #pragma unroll
        for (int m = 0; m < 4; ++m)
            a[m] = *(const half8*)&As[(wrd + m) * 4096 + kt * 512
                                      + hi * 128 + rA * 8];
        #pragma unroll
        for (int m = 0; m < 4; ++m)
            #pragma unroll
            for (int n = 0; n < 4; ++n)
                acc[m][n] = __builtin_amdgcn_mfma_f32_16x16x32_f16(
                    a[m], breg[n][kt], acc[m][n], 0, 0, 0);
    }

    // epilogue: e4 = exp2(-d2*cl2); kernel sum = e+e^2+e^4+e^8+e^16.
    // x = g*2cl2 + (sip+sjp), sip=-cl2*si, sjp=-cl2*sj; clamp x<=0 (== d2>=0).
    const float cl2 = scal[0];
    const float c2  = 2.0f * cl2;
    const int c_lo = lane & 15, r_hi = lane >> 4;
    float sjp[4], sip[4][4];
    #pragma unroll
    for (int n = 0; n < 4; ++n) sjp[n] = -cl2 * sq[col0 + wc + n * 16 + c_lo];
    #pragma unroll
    for (int m = 0; m < 4; ++m)
        #pragma unroll
        for (int r = 0; r < 4; ++r)
            sip[m][r] = -cl2 * sq[row0 + wr + m * 16 + r_hi * 4 + r];

    float part = 0.0f;
    #pragma unroll
    for (int m = 0; m < 4; ++m)
        #pragma unroll
        for (int n = 0; n < 4; ++n)
            #pragma unroll
            for (int r = 0; r < 4; ++r) {
                const float x = fminf(fmaf(acc[m][n][r], c2,
                                           sip[m][r] + sjp[n]), 0.0f);
                float e = exp2f(x);
                float ksum = e;
                e *= e; ksum += e;   // ^2
                e *= e; ksum += e;   // ^4
                e *= e; ksum += e;   // ^8
                e *= e; ksum += e;   // ^16
                part += ksum;
            }

    #pragma unroll
    for (int off = 32; off > 0; off >>= 1) part += __shfl_down(part, off);
    __shared__ float wsum[4];
    if (lane == 0) wsum[w] = part;
    __syncthreads();
    if (tid == 0)
        blockpart[bid] = (wsum[0] + wsum[1] + wsum[2] + wsum[3]) * wfac;
}

// ---------------------------------------------------------------- K4: final reduce
__global__ __launch_bounds__(512) void mmd_final(const float* __restrict__ blockpart,
                                                 float* __restrict__ out) {
    const int t = threadIdx.x;
    double acc = 0.0;
    #pragma unroll
    for (int u = 0; u < 4; ++u) acc += (double)blockpart[t + u * 512];
    if (t < NBLK - 2048) acc += (double)blockpart[t + 2048];
    #pragma unroll
    for (int off = 32; off > 0; off >>= 1) acc += __shfl_down(acc, off);
    __shared__ double sd[8];
    const int lane = t & 63, w = t >> 6;
    if (lane == 0) sd[w] = acc;
    __syncthreads();
    if (t == 0) {
        double tot = 0.0;
        #pragma unroll
        for (int i = 0; i < 8; ++i) tot += sd[i];
        tot /= ((double)NS * (double)NS);
        out[0] = (float)fmax(tot, 0.0);
    }
}

// ---------------------------------------------------------------- launch
extern "C" void kernel_launch(void* const* d_in, const int* in_sizes, int n_in,
                              void* d_out, int out_size, void* d_ws, size_t ws_size,
                              hipStream_t stream) {
    const float* S = (const float*)d_in[0];
    const float* T = (const float*)d_in[1];
    char* ws = (char*)d_ws;
    _Float16* X16   = (_Float16*)(ws + OFF_X16);
    float* sq       = (float*)(ws + OFF_SQ);
    float* colpart  = (float*)(ws + OFF_COLP);
    float* blockpart= (float*)(ws + OFF_BP);
    float* scal     = (float*)(ws + OFF_SCAL);

    mmd_prep<<<256, 256, 0, stream>>>(S, T, X16, sq, colpart);
    mmd_bw<<<1, 1024, 0, stream>>>(colpart, sq, scal);
    mmd_main<<<NBLK, 256, 0, stream>>>(X16, sq, scal, blockpart);
    mmd_final<<<1, 512, 0, stream>>>(blockpart, (float*)d_out);
}

// Round 9
// 56.190 us; speedup vs baseline: 1.2914x; 1.0149x over previous
//
#include <hip/hip_runtime.h>
#include <stdint.h>

typedef _Float16 half4 __attribute__((ext_vector_type(4)));
typedef _Float16 half8 __attribute__((ext_vector_type(8)));
typedef float f32x4 __attribute__((ext_vector_type(4)));

#define NS 4096
#define NTOT 8192
#define DD 256
#define NBLK 2080   // 528 SS lower-tri + 528 TT lower-tri + 1024 ST full

// X16 "tiled4" layout: addr(r,k) = (r>>4)*4096 + (k>>3)*128 + (r&15)*8 + (k&7)
// -> each (16-row, 32-col) K-subtile is one contiguous 1KB block; staging and
// B-fragment loads are wave-uniform base + lane*16B (perfectly coalesced).

// workspace layout (bytes)
#define OFF_X16   0                        // 8192*256*2 = 4 MB fp16 (tiled4)
#define OFF_SQ    (4*1024*1024)            // 8192 floats
#define OFF_COLP  (OFF_SQ + 32*1024)       // 256*256 floats = 256 KB
#define OFF_BP    (OFF_COLP + 256*1024)    // 2080 floats
#define OFF_SCAL  (OFF_BP + 2080*4)        // 1 float (exp2 scale)

// ---------------------------------------------------------------- K1: prep
__global__ __launch_bounds__(256) void mmd_prep(const float* __restrict__ S,
                                                const float* __restrict__ T,
                                                _Float16* __restrict__ X16,
                                                float* __restrict__ sq,
                                                float* __restrict__ colpart) {
    __shared__ _Float16 tile[16][264];     // +8 halves pad: conflict-free reorder
    __shared__ float cl[4][256];
    const int b = blockIdx.x, tid = threadIdx.x;
    const int lane = tid & 63, w = tid >> 6;
    f32x4 cacc = {0.f, 0.f, 0.f, 0.f};
    #pragma unroll
    for (int h = 0; h < 2; ++h) {
        #pragma unroll
        for (int rr = 0; rr < 4; ++rr) {
            const int row = b * 32 + h * 16 + w * 4 + rr;   // wave-uniform
            const float* src = (row < NS) ? (S + (size_t)row * DD)
                                          : (T + (size_t)(row - NS) * DD);
            const f32x4 v = *(const f32x4*)(src + lane * 4);
            cacc += v;
            float vv = v.x * v.x + v.y * v.y + v.z * v.z + v.w * v.w;
            half4 hx = { (_Float16)v.x, (_Float16)v.y, (_Float16)v.z, (_Float16)v.w };
            *(half4*)&tile[w * 4 + rr][lane * 4] = hx;
            #pragma unroll
            for (int off = 32; off; off >>= 1) vv += __shfl_down(vv, off);
            if (lane == 0) sq[row] = vv;
        }
        __syncthreads();
        _Float16* dst = X16 + (size_t)(b * 2 + h) * 4096;
        #pragma unroll
        for (int q = 0; q < 2; ++q) {
            const int c = q * 256 + tid;                    // chunk = kc*16+rl
            *(half8*)(dst + c * 8) = *(const half8*)&tile[c & 15][(c >> 4) * 8];
        }
        __syncthreads();
    }
    *(f32x4*)&cl[w][lane * 4] = cacc;
    __syncthreads();
    colpart[b * 256 + tid] = cl[0][tid] + cl[1][tid] + cl[2][tid] + cl[3][tid];
}

// ---------------------------------------------------------------- K2: bandwidth
__global__ __launch_bounds__(1024) void mmd_bw(const float* __restrict__ colpart,
                                               const float* __restrict__ sq,
                                               float* __restrict__ scal) {
    __shared__ float cpart[4][256];
    __shared__ double sd[16], sf[16];
    const int t = threadIdx.x;
    const int c = t & 255, g = t >> 8;
    float cs = 0.0f;
    #pragma unroll
    for (int b = 0; b < 64; ++b) cs += colpart[((g * 64 + b) << 8) | c];
    cpart[g][c] = cs;
    const f32x4 q0 = *(const f32x4*)(sq + t * 8);
    const f32x4 q1 = *(const f32x4*)(sq + t * 8 + 4);
    double qd = (double)(q0.x + q0.y + q0.z + q0.w) +
                (double)(q1.x + q1.y + q1.z + q1.w);
    __syncthreads();
    double s2 = 0.0;
    if (g == 0) {
        const double tot = (double)cpart[0][c] + cpart[1][c] +
                           cpart[2][c] + cpart[3][c];
        s2 = tot * tot;
    }
    const int lane = t & 63, w = t >> 6;
    #pragma unroll
    for (int off = 32; off; off >>= 1) {
        s2 += __shfl_down(s2, off);
        qd += __shfl_down(qd, off);
    }
    if (lane == 0) { sd[w] = s2; sf[w] = qd; }
    __syncthreads();
    if (t == 0) {
        double s2t = 0.0, qt = 0.0;
        #pragma unroll
        for (int i = 0; i < 16; ++i) { s2t += sd[i]; qt += sf[i]; }
        const double n = (double)NTOT;
        const double sumd2 = 2.0 * n * qt - 2.0 * s2t;
        double bwv = sumd2 / (n * n - n);
        bwv = bwv / 4.0;   // KERNEL_MUL^(KERNEL_NUM//2) = 2^2
        scal[0] = (float)(1.0 / (16.0 * bwv * 0.6931471805599453));
    }
}

// ---------------------------------------------------------------- K3: main GEMM+kernel
// OCCUPANCY-FIRST: LDS = 16KB only (A-tile BK=32 double-buffer); B fragments
// load straight from L2 inside the K-loop (what the compiler chose in r8
// anyway). launch_bounds(256,4) caps VGPR<=128 -> target 4-5 blocks/CU so
// per-block stalls overlap across blocks. tiled4 coalesced loads throughout.
__global__ __launch_bounds__(256, 4) void mmd_main(const _Float16* __restrict__ X16,
                                                   const float* __restrict__ sq,
                                                   const float* __restrict__ scal,
                                                   float* __restrict__ blockpart) {
    __shared__ _Float16 As[2][4096];       // 2 x 8KB A k-slice
    __shared__ float wsum[4];

    // T1: XCD swizzle (2080 % 8 == 0 -> bijective simple form)
    const int bid = (blockIdx.x % 8) * (NBLK / 8) + blockIdx.x / 8;
    int br, bc;
    float wfac;
    if (bid < 1056) {
        int t = bid, base = 0;
        if (t >= 528) { t -= 528; base = 32; }
        int i = (int)((sqrtf(8.0f * (float)t + 1.0f) - 1.0f) * 0.5f);
        while ((i + 1) * (i + 2) / 2 <= t) ++i;
        while (i * (i + 1) / 2 > t) --i;
        const int j = t - i * (i + 1) / 2;
        br = base + i; bc = base + j;
        wfac = (i == j) ? 1.0f : 2.0f;   // off-diag tile counts for (i,j) and (j,i)
    } else {
        const int t = bid - 1056;
        br = t >> 5; bc = 32 + (t & 31);
        wfac = -2.0f;                    // loss has -2*xy
    }
    const int row0 = br * 128, col0 = bc * 128;
    const int tid = threadIdx.x;
    const int lane = tid & 63;
    const int w = tid >> 6;
    const int wrd = (w >> 1) * 4, wcd = (w & 1) * 4;   // 16-row region bases
    const int wr = wrd * 16, wc = wcd * 16;
    const int rA = lane & 15, hi = lane >> 4;
    const int lof = hi * 128 + rA * 8;     // fragment offset within a 1KB region

    // A staging: per step, 512 16B chunks; thread does chunks {tid, 256+tid}.
    const _Float16* Abase = X16 + (size_t)(row0 >> 4) * 4096;
    // B fragments: wave-uniform base + lane*16B per (n, kt)
    const _Float16* Bbase = X16 + ((size_t)(col0 >> 4) + wcd) * 4096 + lof;

    auto STAGE = [&](int s, int kt) {
        #pragma unroll
        for (int i = 0; i < 2; ++i) {
            const int c = i * 256 + tid;               // 0..511
            const _Float16* ga = Abase + (size_t)(c >> 6) * 4096 + kt * 512
                                       + (c & 63) * 8;
            __builtin_amdgcn_global_load_lds(
                (const __attribute__((address_space(1))) uint32_t*)ga,
                (__attribute__((address_space(3))) uint32_t*)&As[s][c * 8], 16, 0, 0);
        }
    };

    f32x4 acc[4][4] = {};
    auto COMPUTE = [&](int s, int kt) {
        half8 a[4], b[4];
        #pragma unroll
        for (int n = 0; n < 4; ++n)
            b[n] = *(const half8*)(Bbase + (size_t)n * 4096 + kt * 512);
        #pragma unroll
        for (int m = 0; m < 4; ++m)
            a[m] = *(const half8*)&As[s][(wrd + m) * 512 + lof];
        __builtin_amdgcn_s_setprio(1);
        #pragma unroll
        for (int m = 0; m < 4; ++m)
            #pragma unroll
            for (int n = 0; n < 4; ++n)
                acc[m][n] = __builtin_amdgcn_mfma_f32_16x16x32_f16(
                    a[m], b[n], acc[m][n], 0, 0, 0);
        __builtin_amdgcn_s_setprio(0);
    };

    STAGE(0, 0);
    __syncthreads();
    #pragma unroll
    for (int kt = 0; kt < 8; ++kt) {
        if (kt < 7) STAGE((kt + 1) & 1, kt + 1);   // prefetch next A slice
        COMPUTE(kt & 1, kt);
        if (kt < 7) __syncthreads();
    }

    // epilogue: e4 = exp2(-d2*cl2); kernel sum = e+e^2+e^4+e^8+e^16.
    const float cl2 = scal[0];
    const float c2  = 2.0f * cl2;
    const int c_lo = lane & 15, r_hi = lane >> 4;
    float sjp[4], sip[4][4];
    #pragma unroll
    for (int n = 0; n < 4; ++n) sjp[n] = -cl2 * sq[col0 + wc + n * 16 + c_lo];
    #pragma unroll
    for (int m = 0; m < 4; ++m)
        #pragma unroll
        for (int r = 0; r < 4; ++r)
            sip[m][r] = -cl2 * sq[row0 + wr + m * 16 + r_hi * 4 + r];

    float part = 0.0f;
    #pragma unroll
    for (int m = 0; m < 4; ++m)
        #pragma unroll
        for (int n = 0; n < 4; ++n)
            #pragma unroll
            for (int r = 0; r < 4; ++r) {
                const float x = fminf(fmaf(acc[m][n][r], c2,
                                           sip[m][r] + sjp[n]), 0.0f);
                float e = exp2f(x);
                float ksum = e;
                e *= e; ksum += e;   // ^2
                e *= e; ksum += e;   // ^4
                e *= e; ksum += e;   // ^8
                e *= e; ksum += e;   // ^16
                part += ksum;
            }

    #pragma unroll
    for (int off = 32; off > 0; off >>= 1) part += __shfl_down(part, off);
    if (lane == 0) wsum[w] = part;
    __syncthreads();
    if (tid == 0)
        blockpart[bid] = (wsum[0] + wsum[1] + wsum[2] + wsum[3]) * wfac;
}

// ---------------------------------------------------------------- K4: final reduce
__global__ __launch_bounds__(512) void mmd_final(const float* __restrict__ blockpart,
                                                 float* __restrict__ out) {
    const int t = threadIdx.x;
    double acc = 0.0;
    #pragma unroll
    for (int u = 0; u < 4; ++u) acc += (double)blockpart[t + u * 512];
    if (t < NBLK - 2048) acc += (double)blockpart[t + 2048];
    #pragma unroll
    for (int off = 32; off > 0; off >>= 1) acc += __shfl_down(acc, off);
    __shared__ double sd[8];
    const int lane = t & 63, w = t >> 6;
    if (lane == 0) sd[w] = acc;
    __syncthreads();
    if (t == 0) {
        double tot = 0.0;
        #pragma unroll
        for (int i = 0; i < 8; ++i) tot += sd[i];
        tot /= ((double)NS * (double)NS);
        out[0] = (float)fmax(tot, 0.0);
    }
}

// ---------------------------------------------------------------- launch
extern "C" void kernel_launch(void* const* d_in, const int* in_sizes, int n_in,
                              void* d_out, int out_size, void* d_ws, size_t ws_size,
                              hipStream_t stream) {
    const float* S = (const float*)d_in[0];
    const float* T = (const float*)d_in[1];
    char* ws = (char*)d_ws;
    _Float16* X16   = (_Float16*)(ws + OFF_X16);
    float* sq       = (float*)(ws + OFF_SQ);
    float* colpart  = (float*)(ws + OFF_COLP);
    float* blockpart= (float*)(ws + OFF_BP);
    float* scal     = (float*)(ws + OFF_SCAL);

    mmd_prep<<<256, 256, 0, stream>>>(S, T, X16, sq, colpart);
    mmd_bw<<<1, 1024, 0, stream>>>(colpart, sq, scal);
    mmd_main<<<NBLK, 256, 0, stream>>>(X16, sq, scal, blockpart);
    mmd_final<<<1, 512, 0, stream>>>(blockpart, (float*)d_out);
}